// Round 1
// baseline (2319.037 us; speedup 1.0000x reference)
//
#include <hip/hip_runtime.h>

// Graphormer-style multi-head attention, fp32 baseline.
// B=16, N=512, HID=1024, H=16, D=64, T_HOP=32, T_EDGE=64, SCALE=1/8.
//
// Pipeline:
//  1) gemm_xwT x3: Q,K,V = x@W^T+b written directly in [B,H,N,D] layout
//  2) type_scores: S_hop[b,h,i,t] = q_i.qhe_t + k_i.khe_t ; S_edge likewise
//  3) attn_fused: flash-style softmax over j with bias gathered from
//     S_hop/S_edge via hop/edge indices; online bin accumulation (vha/vea)
//     in LDS; epilogue folds x1 + vha@vhe + vea@vee, writes Y [B,N,HID]
//  4) gemm_xwT: out = Y@Wo^T+bo
//
// ws layout (floats): Q(8388608) K(8388608) V(8388608) S_hop(4194304)
//                     S_edge(8388608) Y(8388608)  => 184.5 MB total

#define SCALE 0.125f

// ---------------------------------------------------------------------------
// GEMM: C = A @ W^T + bias.  A:[8192,1024], W:[1024,1024] row-major.
// layout==0: C[m*1024+n] plain; layout==1: QKV layout ((b*16+h)*512+i)*64+d.
// BM=BN=128, BK=16, 256 threads, 8x8 micro-tile, k-major LDS (+4 pad).
// ---------------------------------------------------------------------------
__global__ __launch_bounds__(256) void gemm_xwT(
    const float* __restrict__ A, const float* __restrict__ W,
    const float* __restrict__ bias, float* __restrict__ C, int layout)
{
    __shared__ float As[16][132];
    __shared__ float Bs[16][132];
    const int tid = threadIdx.x;
    const int tx = tid & 15, ty = tid >> 4;
    const int m0 = blockIdx.x * 128, n0 = blockIdx.y * 128;
    const int lrow = tid >> 2;          // 0..63
    const int lc4  = (tid & 3) << 2;    // 0,4,8,12

    float acc[8][8];
#pragma unroll
    for (int i = 0; i < 8; ++i)
#pragma unroll
        for (int j = 0; j < 8; ++j) acc[i][j] = 0.f;

    for (int k0 = 0; k0 < 1024; k0 += 16) {
        float4 a0 = *(const float4*)&A[(m0 + lrow) * 1024 + k0 + lc4];
        float4 a1 = *(const float4*)&A[(m0 + 64 + lrow) * 1024 + k0 + lc4];
        float4 b0 = *(const float4*)&W[(n0 + lrow) * 1024 + k0 + lc4];
        float4 b1 = *(const float4*)&W[(n0 + 64 + lrow) * 1024 + k0 + lc4];
        __syncthreads();
        As[lc4 + 0][lrow] = a0.x; As[lc4 + 1][lrow] = a0.y;
        As[lc4 + 2][lrow] = a0.z; As[lc4 + 3][lrow] = a0.w;
        As[lc4 + 0][64 + lrow] = a1.x; As[lc4 + 1][64 + lrow] = a1.y;
        As[lc4 + 2][64 + lrow] = a1.z; As[lc4 + 3][64 + lrow] = a1.w;
        Bs[lc4 + 0][lrow] = b0.x; Bs[lc4 + 1][lrow] = b0.y;
        Bs[lc4 + 2][lrow] = b0.z; Bs[lc4 + 3][lrow] = b0.w;
        Bs[lc4 + 0][64 + lrow] = b1.x; Bs[lc4 + 1][64 + lrow] = b1.y;
        Bs[lc4 + 2][64 + lrow] = b1.z; Bs[lc4 + 3][64 + lrow] = b1.w;
        __syncthreads();
#pragma unroll
        for (int kk = 0; kk < 16; ++kk) {
            float4 av0 = *(const float4*)&As[kk][ty * 4];
            float4 av1 = *(const float4*)&As[kk][64 + ty * 4];
            float4 bv0 = *(const float4*)&Bs[kk][tx * 4];
            float4 bv1 = *(const float4*)&Bs[kk][64 + tx * 4];
            float a[8] = {av0.x, av0.y, av0.z, av0.w, av1.x, av1.y, av1.z, av1.w};
            float bb[8] = {bv0.x, bv0.y, bv0.z, bv0.w, bv1.x, bv1.y, bv1.z, bv1.w};
#pragma unroll
            for (int i = 0; i < 8; ++i)
#pragma unroll
                for (int j = 0; j < 8; ++j) acc[i][j] += a[i] * bb[j];
        }
    }

#pragma unroll
    for (int i = 0; i < 8; ++i) {
        int m = m0 + ((i < 4) ? (ty * 4 + i) : (64 + ty * 4 + (i - 4)));
#pragma unroll
        for (int jh = 0; jh < 2; ++jh) {
            int n = n0 + jh * 64 + tx * 4;
            float4 bb4 = *(const float4*)&bias[n];
            float4 v;
            v.x = acc[i][jh * 4 + 0] + bb4.x;
            v.y = acc[i][jh * 4 + 1] + bb4.y;
            v.z = acc[i][jh * 4 + 2] + bb4.z;
            v.w = acc[i][jh * 4 + 3] + bb4.w;
            if (layout == 0) {
                *(float4*)&C[m * 1024 + n] = v;
            } else {
                int bb_ = m >> 9, i2 = m & 511, hh = n >> 6, dd = n & 63;
                *(float4*)&C[((bb_ * 16 + hh) * 512 + i2) * 64 + dd] = v;
            }
        }
    }
}

// ---------------------------------------------------------------------------
// Type scores: S_hop[(bh*512+i)*32+t] = sum_d q*qhe + k*khe ; S_edge likewise.
// Block = (bh, 64 rows). 256 threads: lane i=tid&63, quarter tq=tid>>6, each
// thread computes 24 t-values (wave-uniform t => broadcast emb reads).
// ---------------------------------------------------------------------------
__global__ __launch_bounds__(256) void type_scores(
    const float* __restrict__ Q, const float* __restrict__ K,
    const float* __restrict__ qhe, const float* __restrict__ qee,
    const float* __restrict__ khe, const float* __restrict__ kee,
    float* __restrict__ Shop, float* __restrict__ Sedge)
{
    __shared__ float qs[64][65];
    __shared__ float ks[64][65];
    const int tid = threadIdx.x;
    const int i0 = (blockIdx.x & 7) * 64;
    const int bh = blockIdx.x >> 3;
    const int h = bh & 15;
    {
        const int r = tid >> 2, c16 = (tid & 3) << 4;
        const float* qp = Q + (bh * 512 + i0 + r) * 64 + c16;
        const float* kp = K + (bh * 512 + i0 + r) * 64 + c16;
#pragma unroll
        for (int u = 0; u < 4; ++u) {
            float4 q4 = *(const float4*)(qp + u * 4);
            float4 k4 = *(const float4*)(kp + u * 4);
            qs[r][c16 + u * 4 + 0] = q4.x; qs[r][c16 + u * 4 + 1] = q4.y;
            qs[r][c16 + u * 4 + 2] = q4.z; qs[r][c16 + u * 4 + 3] = q4.w;
            ks[r][c16 + u * 4 + 0] = k4.x; ks[r][c16 + u * 4 + 1] = k4.y;
            ks[r][c16 + u * 4 + 2] = k4.z; ks[r][c16 + u * 4 + 3] = k4.w;
        }
    }
    __syncthreads();
    const int i = tid & 63;
    const int tq = tid >> 6;
    for (int tt = 0; tt < 24; ++tt) {
        int t96 = tq * 24 + tt;
        const float *eq, *ek;
        float* outp;
        if (t96 < 32) {
            eq = qhe + t96 * 1024 + h * 64;
            ek = khe + t96 * 1024 + h * 64;
            outp = &Shop[(bh * 512 + i0 + i) * 32 + t96];
        } else {
            int t = t96 - 32;
            eq = qee + t * 1024 + h * 64;
            ek = kee + t * 1024 + h * 64;
            outp = &Sedge[(bh * 512 + i0 + i) * 64 + t];
        }
        float s0 = 0.f, s1 = 0.f, s2 = 0.f, s3 = 0.f;
#pragma unroll 4
        for (int d = 0; d < 64; d += 4) {
            s0 += qs[i][d + 0] * eq[d + 0] + ks[i][d + 0] * ek[d + 0];
            s1 += qs[i][d + 1] * eq[d + 1] + ks[i][d + 1] * ek[d + 1];
            s2 += qs[i][d + 2] * eq[d + 2] + ks[i][d + 2] * ek[d + 2];
            s3 += qs[i][d + 3] * eq[d + 3] + ks[i][d + 3] * ek[d + 3];
        }
        *outp = (s0 + s1) + (s2 + s3);
    }
}

// ---------------------------------------------------------------------------
// Fused attention. Block = (b, h, 32 q-rows). 256 threads.
// Per 64-j tile: QK^T (2x4 micro) -> bias gather + online softmax + LDS-atomic
// bin accumulate -> PV. Epilogue: x1 + vha@vhe + vea@vee, normalize, write Y.
// LDS: 77.8 KB => 2 blocks/CU.
// ---------------------------------------------------------------------------
__global__ __launch_bounds__(256) void attn_fused(
    const float* __restrict__ Qg, const float* __restrict__ Kg,
    const float* __restrict__ Vg,
    const float* __restrict__ Shop, const float* __restrict__ Sedge,
    const int* __restrict__ hop, const int* __restrict__ edge,
    const float* __restrict__ vhe, const float* __restrict__ vee,
    float* __restrict__ Y)
{
    __shared__ float qs[64][36];      // [d][i]
    __shared__ float Ks[64][68];      // [d][j]
    __shared__ float Vs[64][68];      // [j][d]
    __shared__ float Ss[32][68];      // [i][j] raw scores then p
    __shared__ float ShopS[32][33];
    __shared__ float SedgeS[32][65];
    __shared__ float vhaS[32][33];
    __shared__ float veaS[32][65];

    const int tid = threadIdx.x;
    const int i0 = blockIdx.x * 32;
    const int h = blockIdx.y;
    const int b = blockIdx.z;
    const int bh = b * 16 + h;

    const int pr = tid >> 3;          // row 0..31 (phases b/c)
    const int ps = tid & 7;           // slot 0..7
    const int tx = tid & 15, ty = tid >> 4;  // phase a

    // ---- prologue: stage q rows (transposed), bias rows, zero bins ----
    {
        const float* qp = Qg + (bh * 512 + i0 + pr) * 64 + ps * 8;
        float4 q0 = *(const float4*)qp;
        float4 q1 = *(const float4*)(qp + 4);
        qs[ps * 8 + 0][pr] = q0.x; qs[ps * 8 + 1][pr] = q0.y;
        qs[ps * 8 + 2][pr] = q0.z; qs[ps * 8 + 3][pr] = q0.w;
        qs[ps * 8 + 4][pr] = q1.x; qs[ps * 8 + 5][pr] = q1.y;
        qs[ps * 8 + 6][pr] = q1.z; qs[ps * 8 + 7][pr] = q1.w;

        float4 sh = *(const float4*)&Shop[(bh * 512 + i0 + pr) * 32 + ps * 4];
        ShopS[pr][ps * 4 + 0] = sh.x; ShopS[pr][ps * 4 + 1] = sh.y;
        ShopS[pr][ps * 4 + 2] = sh.z; ShopS[pr][ps * 4 + 3] = sh.w;
        float4 se0 = *(const float4*)&Sedge[(bh * 512 + i0 + pr) * 64 + ps * 8];
        float4 se1 = *(const float4*)&Sedge[(bh * 512 + i0 + pr) * 64 + ps * 8 + 4];
        SedgeS[pr][ps * 8 + 0] = se0.x; SedgeS[pr][ps * 8 + 1] = se0.y;
        SedgeS[pr][ps * 8 + 2] = se0.z; SedgeS[pr][ps * 8 + 3] = se0.w;
        SedgeS[pr][ps * 8 + 4] = se1.x; SedgeS[pr][ps * 8 + 5] = se1.y;
        SedgeS[pr][ps * 8 + 6] = se1.z; SedgeS[pr][ps * 8 + 7] = se1.w;

#pragma unroll
        for (int u = 0; u < 4; ++u) vhaS[pr][ps * 4 + u] = 0.f;
#pragma unroll
        for (int u = 0; u < 8; ++u) veaS[pr][ps * 8 + u] = 0.f;
    }

    float m_run = -1e30f, l_run = 0.f;
    float acc[8];
#pragma unroll
    for (int u = 0; u < 8; ++u) acc[u] = 0.f;

    const int lr = tid >> 2;          // 0..63 (tile loads)
    const int lq = tid & 3;

    for (int j0 = 0; j0 < 512; j0 += 64) {
        // ---- stage K (transposed) and V tiles ----
        const float* Kp = Kg + (bh * 512 + j0 + lr) * 64;
        const float* Vp = Vg + (bh * 512 + j0 + lr) * 64;
        float4 kv[4], vv[4];
#pragma unroll
        for (int u = 0; u < 4; ++u) {
            kv[u] = *(const float4*)(Kp + lq * 4 + u * 16);
            vv[u] = *(const float4*)(Vp + lq * 4 + u * 16);
        }
        __syncthreads();   // prev tile's compute done
#pragma unroll
        for (int u = 0; u < 4; ++u) {
            int d = lq * 4 + u * 16;
            Ks[d + 0][lr] = kv[u].x; Ks[d + 1][lr] = kv[u].y;
            Ks[d + 2][lr] = kv[u].z; Ks[d + 3][lr] = kv[u].w;
            *(float4*)&Vs[lr][d] = vv[u];
        }
        __syncthreads();

        // ---- phase a: raw QK^T for this tile ----
        {
            float accs[2][4];
#pragma unroll
            for (int ii = 0; ii < 2; ++ii)
#pragma unroll
                for (int jj = 0; jj < 4; ++jj) accs[ii][jj] = 0.f;
#pragma unroll 8
            for (int d = 0; d < 64; ++d) {
                float2 aa = *(const float2*)&qs[d][ty * 2];
                float4 bb = *(const float4*)&Ks[d][tx * 4];
                accs[0][0] += aa.x * bb.x; accs[0][1] += aa.x * bb.y;
                accs[0][2] += aa.x * bb.z; accs[0][3] += aa.x * bb.w;
                accs[1][0] += aa.y * bb.x; accs[1][1] += aa.y * bb.y;
                accs[1][2] += aa.y * bb.z; accs[1][3] += aa.y * bb.w;
            }
            *(float4*)&Ss[ty * 2 + 0][tx * 4] =
                make_float4(accs[0][0], accs[0][1], accs[0][2], accs[0][3]);
            *(float4*)&Ss[ty * 2 + 1][tx * 4] =
                make_float4(accs[1][0], accs[1][1], accs[1][2], accs[1][3]);
        }
        __syncthreads();

        // ---- phase b: bias gather + online softmax + bins ----
        const int* hp = hop + (b * 512 + i0 + pr) * 512 + j0 + ps * 8;
        const int* ep = edge + (b * 512 + i0 + pr) * 512 + j0 + ps * 8;
        int4 h0 = *(const int4*)hp, h1 = *(const int4*)(hp + 4);
        int4 e0 = *(const int4*)ep, e1 = *(const int4*)(ep + 4);
        int hv[8] = {h0.x, h0.y, h0.z, h0.w, h1.x, h1.y, h1.z, h1.w};
        int ev[8] = {e0.x, e0.y, e0.z, e0.w, e1.x, e1.y, e1.z, e1.w};
        float p[8];
        float tmax = -1e30f;
#pragma unroll
        for (int u = 0; u < 8; ++u) {
            float val = (Ss[pr][ps * 8 + u] + ShopS[pr][hv[u]] + SedgeS[pr][ev[u]]) * SCALE;
            p[u] = val;
            tmax = fmaxf(tmax, val);
        }
        tmax = fmaxf(tmax, __shfl_xor(tmax, 1));
        tmax = fmaxf(tmax, __shfl_xor(tmax, 2));
        tmax = fmaxf(tmax, __shfl_xor(tmax, 4));
        float m_new = fmaxf(m_run, tmax);
        float alpha = __expf(m_run - m_new);
        float psum = 0.f;
#pragma unroll
        for (int u = 0; u < 8; ++u) {
            p[u] = __expf(p[u] - m_new);
            psum += p[u];
        }
        psum += __shfl_xor(psum, 1);
        psum += __shfl_xor(psum, 2);
        psum += __shfl_xor(psum, 4);
        l_run = l_run * alpha + psum;
        m_run = m_new;
#pragma unroll
        for (int u = 0; u < 8; ++u) acc[u] *= alpha;
#pragma unroll
        for (int u = 0; u < 4; ++u) vhaS[pr][ps * 4 + u] *= alpha;
#pragma unroll
        for (int u = 0; u < 8; ++u) veaS[pr][ps * 8 + u] *= alpha;
#pragma unroll
        for (int u = 0; u < 8; ++u) Ss[pr][ps * 8 + u] = p[u];
        __syncthreads();   // bins rescaled & p visible before adds / PV
#pragma unroll
        for (int u = 0; u < 8; ++u) {
            atomicAdd(&vhaS[pr][hv[u]], p[u]);
            atomicAdd(&veaS[pr][ev[u]], p[u]);
        }

        // ---- phase c: PV accumulate (unnormalized) ----
#pragma unroll 4
        for (int j = 0; j < 64; ++j) {
            float pj = Ss[pr][j];
            float4 v0 = *(const float4*)&Vs[j][ps * 8];
            float4 v1 = *(const float4*)&Vs[j][ps * 8 + 4];
            acc[0] += pj * v0.x; acc[1] += pj * v0.y;
            acc[2] += pj * v0.z; acc[3] += pj * v0.w;
            acc[4] += pj * v1.x; acc[5] += pj * v1.y;
            acc[6] += pj * v1.z; acc[7] += pj * v1.w;
        }
    }
    __syncthreads();   // all bin atomics done

    // ---- epilogue: x1 + vha@vhe + vea@vee, normalize, store ----
    float inv = 1.0f / l_run;
    float o[8];
#pragma unroll
    for (int u = 0; u < 8; ++u) o[u] = acc[u];
    for (int t = 0; t < 32; ++t) {
        float w = vhaS[pr][t];
        float4 g0 = *(const float4*)&vhe[t * 1024 + h * 64 + ps * 8];
        float4 g1 = *(const float4*)&vhe[t * 1024 + h * 64 + ps * 8 + 4];
        o[0] += w * g0.x; o[1] += w * g0.y; o[2] += w * g0.z; o[3] += w * g0.w;
        o[4] += w * g1.x; o[5] += w * g1.y; o[6] += w * g1.z; o[7] += w * g1.w;
    }
    for (int t = 0; t < 64; ++t) {
        float w = veaS[pr][t];
        float4 g0 = *(const float4*)&vee[t * 1024 + h * 64 + ps * 8];
        float4 g1 = *(const float4*)&vee[t * 1024 + h * 64 + ps * 8 + 4];
        o[0] += w * g0.x; o[1] += w * g0.y; o[2] += w * g0.z; o[3] += w * g0.w;
        o[4] += w * g1.x; o[5] += w * g1.y; o[6] += w * g1.z; o[7] += w * g1.w;
    }
    float* yp = Y + (b * 512 + i0 + pr) * 1024 + h * 64 + ps * 8;
    *(float4*)yp = make_float4(o[0] * inv, o[1] * inv, o[2] * inv, o[3] * inv);
    *(float4*)(yp + 4) = make_float4(o[4] * inv, o[5] * inv, o[6] * inv, o[7] * inv);
}

// ---------------------------------------------------------------------------
extern "C" void kernel_launch(void* const* d_in, const int* in_sizes, int n_in,
                              void* d_out, int out_size, void* d_ws, size_t ws_size,
                              hipStream_t stream)
{
    (void)in_sizes; (void)n_in; (void)out_size; (void)ws_size;
    const float* x   = (const float*)d_in[0];
    const float* qhe = (const float*)d_in[1];
    const float* qee = (const float*)d_in[2];
    const float* khe = (const float*)d_in[3];
    const float* kee = (const float*)d_in[4];
    const float* vhe = (const float*)d_in[5];
    const float* vee = (const float*)d_in[6];
    const int*   hop = (const int*)d_in[7];
    const int*   edg = (const int*)d_in[8];
    const float* Wq = (const float*)d_in[9];  const float* bq = (const float*)d_in[10];
    const float* Wk = (const float*)d_in[11]; const float* bk = (const float*)d_in[12];
    const float* Wv = (const float*)d_in[13]; const float* bv = (const float*)d_in[14];
    const float* Wo = (const float*)d_in[15]; const float* bo = (const float*)d_in[16];

    float* ws    = (float*)d_ws;
    float* Qb    = ws;                    // 8388608 floats
    float* Kb    = Qb + 8388608;
    float* Vb    = Kb + 8388608;
    float* Shop  = Vb + 8388608;          // 4194304
    float* Sedge = Shop + 4194304;        // 8388608
    float* Yb    = Sedge + 8388608;       // 8388608   (total 184.5 MB)

    dim3 gGemm(64, 8);
    gemm_xwT<<<gGemm, 256, 0, stream>>>(x, Wq, bq, Qb, 1);
    gemm_xwT<<<gGemm, 256, 0, stream>>>(x, Wk, bk, Kb, 1);
    gemm_xwT<<<gGemm, 256, 0, stream>>>(x, Wv, bv, Vb, 1);
    type_scores<<<2048, 256, 0, stream>>>(Qb, Kb, qhe, qee, khe, kee, Shop, Sedge);
    attn_fused<<<dim3(16, 16, 16), 256, 0, stream>>>(Qb, Kb, Vb, Shop, Sedge,
                                                     hop, edg, vhe, vee, Yb);
    gemm_xwT<<<gGemm, 256, 0, stream>>>(Yb, Wo, bo, (float*)d_out, 0);
}

// Round 2
// 2311.300 us; speedup vs baseline: 1.0033x; 1.0033x over previous
//
#include <hip/hip_runtime.h>

// Graphormer-style multi-head attention, fp32.
// B=16, N=512, HID=1024, H=16, D=64, T_HOP=32, T_EDGE=64, SCALE=1/8.
//
// R2 change: attn_fused restructured for latency.
//  - wave-local row mapping: wave w owns q-rows 8w..8w+7 in ALL phases
//    (QK^T rows 2*(tid>>4), softmax/PV rows tid>>3 — same set per wave),
//    so S/bias/bin LDS traffic is intra-wave => NO barriers between phases.
//  - 2 barriers per j-tile (K/V staging only), down from 4.
//  - K/V global->reg prefetch for tile t+1 issued right after barrier B
//    (so __syncthreads' vmcnt drain is free); hop/edge idx prefetched
//    before QK^T, consumed ~4K cycles later in softmax.
//  - Ss stride 65 (odd) + scalar stores: 2-way banks instead of 8-way.
//
// ws layout (floats): Q(8388608) K(8388608) V(8388608) S_hop(4194304)
//                     S_edge(8388608) Y(8388608)  => 184.5 MB total

#define SCALE 0.125f

// ---------------------------------------------------------------------------
// GEMM: C = A @ W^T + bias.  A:[8192,1024], W:[1024,1024] row-major.
// layout==0: C[m*1024+n] plain; layout==1: QKV layout ((b*16+h)*512+i)*64+d.
// (unchanged from R1)
// ---------------------------------------------------------------------------
__global__ __launch_bounds__(256) void gemm_xwT(
    const float* __restrict__ A, const float* __restrict__ W,
    const float* __restrict__ bias, float* __restrict__ C, int layout)
{
    __shared__ float As[16][132];
    __shared__ float Bs[16][132];
    const int tid = threadIdx.x;
    const int tx = tid & 15, ty = tid >> 4;
    const int m0 = blockIdx.x * 128, n0 = blockIdx.y * 128;
    const int lrow = tid >> 2;          // 0..63
    const int lc4  = (tid & 3) << 2;    // 0,4,8,12

    float acc[8][8];
#pragma unroll
    for (int i = 0; i < 8; ++i)
#pragma unroll
        for (int j = 0; j < 8; ++j) acc[i][j] = 0.f;

    for (int k0 = 0; k0 < 1024; k0 += 16) {
        float4 a0 = *(const float4*)&A[(m0 + lrow) * 1024 + k0 + lc4];
        float4 a1 = *(const float4*)&A[(m0 + 64 + lrow) * 1024 + k0 + lc4];
        float4 b0 = *(const float4*)&W[(n0 + lrow) * 1024 + k0 + lc4];
        float4 b1 = *(const float4*)&W[(n0 + 64 + lrow) * 1024 + k0 + lc4];
        __syncthreads();
        As[lc4 + 0][lrow] = a0.x; As[lc4 + 1][lrow] = a0.y;
        As[lc4 + 2][lrow] = a0.z; As[lc4 + 3][lrow] = a0.w;
        As[lc4 + 0][64 + lrow] = a1.x; As[lc4 + 1][64 + lrow] = a1.y;
        As[lc4 + 2][64 + lrow] = a1.z; As[lc4 + 3][64 + lrow] = a1.w;
        Bs[lc4 + 0][lrow] = b0.x; Bs[lc4 + 1][lrow] = b0.y;
        Bs[lc4 + 2][lrow] = b0.z; Bs[lc4 + 3][lrow] = b0.w;
        Bs[lc4 + 0][64 + lrow] = b1.x; Bs[lc4 + 1][64 + lrow] = b1.y;
        Bs[lc4 + 2][64 + lrow] = b1.z; Bs[lc4 + 3][64 + lrow] = b1.w;
        __syncthreads();
#pragma unroll
        for (int kk = 0; kk < 16; ++kk) {
            float4 av0 = *(const float4*)&As[kk][ty * 4];
            float4 av1 = *(const float4*)&As[kk][64 + ty * 4];
            float4 bv0 = *(const float4*)&Bs[kk][tx * 4];
            float4 bv1 = *(const float4*)&Bs[kk][64 + tx * 4];
            float a[8] = {av0.x, av0.y, av0.z, av0.w, av1.x, av1.y, av1.z, av1.w};
            float bb[8] = {bv0.x, bv0.y, bv0.z, bv0.w, bv1.x, bv1.y, bv1.z, bv1.w};
#pragma unroll
            for (int i = 0; i < 8; ++i)
#pragma unroll
                for (int j = 0; j < 8; ++j) acc[i][j] += a[i] * bb[j];
        }
    }

#pragma unroll
    for (int i = 0; i < 8; ++i) {
        int m = m0 + ((i < 4) ? (ty * 4 + i) : (64 + ty * 4 + (i - 4)));
#pragma unroll
        for (int jh = 0; jh < 2; ++jh) {
            int n = n0 + jh * 64 + tx * 4;
            float4 bb4 = *(const float4*)&bias[n];
            float4 v;
            v.x = acc[i][jh * 4 + 0] + bb4.x;
            v.y = acc[i][jh * 4 + 1] + bb4.y;
            v.z = acc[i][jh * 4 + 2] + bb4.z;
            v.w = acc[i][jh * 4 + 3] + bb4.w;
            if (layout == 0) {
                *(float4*)&C[m * 1024 + n] = v;
            } else {
                int bb_ = m >> 9, i2 = m & 511, hh = n >> 6, dd = n & 63;
                *(float4*)&C[((bb_ * 16 + hh) * 512 + i2) * 64 + dd] = v;
            }
        }
    }
}

// ---------------------------------------------------------------------------
// Type scores (unchanged from R1).
// ---------------------------------------------------------------------------
__global__ __launch_bounds__(256) void type_scores(
    const float* __restrict__ Q, const float* __restrict__ K,
    const float* __restrict__ qhe, const float* __restrict__ qee,
    const float* __restrict__ khe, const float* __restrict__ kee,
    float* __restrict__ Shop, float* __restrict__ Sedge)
{
    __shared__ float qs[64][65];
    __shared__ float ks[64][65];
    const int tid = threadIdx.x;
    const int i0 = (blockIdx.x & 7) * 64;
    const int bh = blockIdx.x >> 3;
    const int h = bh & 15;
    {
        const int r = tid >> 2, c16 = (tid & 3) << 4;
        const float* qp = Q + (bh * 512 + i0 + r) * 64 + c16;
        const float* kp = K + (bh * 512 + i0 + r) * 64 + c16;
#pragma unroll
        for (int u = 0; u < 4; ++u) {
            float4 q4 = *(const float4*)(qp + u * 4);
            float4 k4 = *(const float4*)(kp + u * 4);
            qs[r][c16 + u * 4 + 0] = q4.x; qs[r][c16 + u * 4 + 1] = q4.y;
            qs[r][c16 + u * 4 + 2] = q4.z; qs[r][c16 + u * 4 + 3] = q4.w;
            ks[r][c16 + u * 4 + 0] = k4.x; ks[r][c16 + u * 4 + 1] = k4.y;
            ks[r][c16 + u * 4 + 2] = k4.z; ks[r][c16 + u * 4 + 3] = k4.w;
        }
    }
    __syncthreads();
    const int i = tid & 63;
    const int tq = tid >> 6;
    for (int tt = 0; tt < 24; ++tt) {
        int t96 = tq * 24 + tt;
        const float *eq, *ek;
        float* outp;
        if (t96 < 32) {
            eq = qhe + t96 * 1024 + h * 64;
            ek = khe + t96 * 1024 + h * 64;
            outp = &Shop[(bh * 512 + i0 + i) * 32 + t96];
        } else {
            int t = t96 - 32;
            eq = qee + t * 1024 + h * 64;
            ek = kee + t * 1024 + h * 64;
            outp = &Sedge[(bh * 512 + i0 + i) * 64 + t];
        }
        float s0 = 0.f, s1 = 0.f, s2 = 0.f, s3 = 0.f;
#pragma unroll 4
        for (int d = 0; d < 64; d += 4) {
            s0 += qs[i][d + 0] * eq[d + 0] + ks[i][d + 0] * ek[d + 0];
            s1 += qs[i][d + 1] * eq[d + 1] + ks[i][d + 1] * ek[d + 1];
            s2 += qs[i][d + 2] * eq[d + 2] + ks[i][d + 2] * ek[d + 2];
            s3 += qs[i][d + 3] * eq[d + 3] + ks[i][d + 3] * ek[d + 3];
        }
        *outp = (s0 + s1) + (s2 + s3);
    }
}

// ---------------------------------------------------------------------------
// Fused attention, R2. Block = (b, h, 32 q-rows), 256 threads = 4 waves.
// Wave w exclusively owns q-rows 8w..8w+7 => all S/bias/bin LDS traffic is
// intra-wave; only K/V staging needs barriers (2 per tile).
// ---------------------------------------------------------------------------
__global__ __launch_bounds__(256) void attn_fused(
    const float* __restrict__ Qg, const float* __restrict__ Kg,
    const float* __restrict__ Vg,
    const float* __restrict__ Shop, const float* __restrict__ Sedge,
    const int* __restrict__ hop, const int* __restrict__ edge,
    const float* __restrict__ vhe, const float* __restrict__ vee,
    float* __restrict__ Y)
{
    __shared__ float qs[64][36];      // [d][i]
    __shared__ float Ks[64][68];      // [d][j]
    __shared__ float Vs[64][68];      // [j][d]
    __shared__ float Ss[32][65];      // [i][j] raw scores then p (odd stride)
    __shared__ float ShopS[32][33];
    __shared__ float SedgeS[32][65];
    __shared__ float vhaS[32][33];
    __shared__ float veaS[32][65];

    const int tid = threadIdx.x;
    const int i0 = blockIdx.x * 32;
    const int h = blockIdx.y;
    const int b = blockIdx.z;
    const int bh = b * 16 + h;

    const int pr = tid >> 3;          // row 0..31; wave w has pr in [8w,8w+8)
    const int ps = tid & 7;           // slot 0..7
    const int tx = tid & 15;          // QK^T col group
    const int r0 = (tid >> 4) * 2;    // QK^T rows r0,r0+1 — same wave's rows

    // ---- prologue: stage q (transposed), bias rows, zero bins (wave-local) ----
    {
        const float* qp = Qg + (bh * 512 + i0 + pr) * 64 + ps * 8;
        float4 q0 = *(const float4*)qp;
        float4 q1 = *(const float4*)(qp + 4);
        qs[ps * 8 + 0][pr] = q0.x; qs[ps * 8 + 1][pr] = q0.y;
        qs[ps * 8 + 2][pr] = q0.z; qs[ps * 8 + 3][pr] = q0.w;
        qs[ps * 8 + 4][pr] = q1.x; qs[ps * 8 + 5][pr] = q1.y;
        qs[ps * 8 + 6][pr] = q1.z; qs[ps * 8 + 7][pr] = q1.w;

        float4 sh = *(const float4*)&Shop[(bh * 512 + i0 + pr) * 32 + ps * 4];
        ShopS[pr][ps * 4 + 0] = sh.x; ShopS[pr][ps * 4 + 1] = sh.y;
        ShopS[pr][ps * 4 + 2] = sh.z; ShopS[pr][ps * 4 + 3] = sh.w;
        float4 se0 = *(const float4*)&Sedge[(bh * 512 + i0 + pr) * 64 + ps * 8];
        float4 se1 = *(const float4*)&Sedge[(bh * 512 + i0 + pr) * 64 + ps * 8 + 4];
        SedgeS[pr][ps * 8 + 0] = se0.x; SedgeS[pr][ps * 8 + 1] = se0.y;
        SedgeS[pr][ps * 8 + 2] = se0.z; SedgeS[pr][ps * 8 + 3] = se0.w;
        SedgeS[pr][ps * 8 + 4] = se1.x; SedgeS[pr][ps * 8 + 5] = se1.y;
        SedgeS[pr][ps * 8 + 6] = se1.z; SedgeS[pr][ps * 8 + 7] = se1.w;

#pragma unroll
        for (int u = 0; u < 4; ++u) vhaS[pr][ps * 4 + u] = 0.f;
#pragma unroll
        for (int u = 0; u < 8; ++u) veaS[pr][ps * 8 + u] = 0.f;
    }
    // no barrier: prologue data consumed only by the staging wave itself

    float m_run = -1e30f, l_run = 0.f;
    float acc[8];
#pragma unroll
    for (int u = 0; u < 8; ++u) acc[u] = 0.f;

    const int lr = tid >> 2;          // staging j-row 0..63
    const int lq = tid & 3;

    // preload K/V tile 0 into registers
    float4 kv[4], vv[4];
    {
        const float* Kp = Kg + (bh * 512 + lr) * 64;
        const float* Vp = Vg + (bh * 512 + lr) * 64;
#pragma unroll
        for (int u = 0; u < 4; ++u) {
            kv[u] = *(const float4*)(Kp + lq * 4 + u * 16);
            vv[u] = *(const float4*)(Vp + lq * 4 + u * 16);
        }
    }

    for (int t = 0; t < 8; ++t) {
        const int j0 = t * 64;
        __syncthreads();               // (A) everyone done reading K/V of t-1
        // write LDS tile t from regs (K transposed, V row-major)
#pragma unroll
        for (int u = 0; u < 4; ++u) {
            int d = lq * 4 + u * 16;
            Ks[d + 0][lr] = kv[u].x; Ks[d + 1][lr] = kv[u].y;
            Ks[d + 2][lr] = kv[u].z; Ks[d + 3][lr] = kv[u].w;
            *(float4*)&Vs[lr][d] = vv[u];
        }
        __syncthreads();               // (B) tile t visible to all waves

        // prefetch K/V tile t+1 (lands during this tile's compute; the
        // vmcnt drain at next barrier A is then free)
        {
            int jn = (t < 7) ? (j0 + 64) : 0;
            const float* Kp = Kg + (bh * 512 + jn + lr) * 64;
            const float* Vp = Vg + (bh * 512 + jn + lr) * 64;
#pragma unroll
            for (int u = 0; u < 4; ++u) {
                kv[u] = *(const float4*)(Kp + lq * 4 + u * 16);
                vv[u] = *(const float4*)(Vp + lq * 4 + u * 16);
            }
        }
        // prefetch hop/edge indices for THIS tile (used after QK^T ~4K cyc)
        const int* hp = hop + (b * 512 + i0 + pr) * 512 + j0 + ps * 8;
        const int* ep = edge + (b * 512 + i0 + pr) * 512 + j0 + ps * 8;
        int4 h0 = *(const int4*)hp, h1 = *(const int4*)(hp + 4);
        int4 e0 = *(const int4*)ep, e1 = *(const int4*)(ep + 4);

        // ---- phase a: QK^T rows r0,r0+1 (wave-local rows) ----
        {
            float a0[4] = {0.f, 0.f, 0.f, 0.f};
            float a1[4] = {0.f, 0.f, 0.f, 0.f};
#pragma unroll 8
            for (int d = 0; d < 64; ++d) {
                float2 aa = *(const float2*)&qs[d][r0];
                float4 bb = *(const float4*)&Ks[d][tx * 4];
                a0[0] += aa.x * bb.x; a0[1] += aa.x * bb.y;
                a0[2] += aa.x * bb.z; a0[3] += aa.x * bb.w;
                a1[0] += aa.y * bb.x; a1[1] += aa.y * bb.y;
                a1[2] += aa.y * bb.z; a1[3] += aa.y * bb.w;
            }
#pragma unroll
            for (int jj = 0; jj < 4; ++jj) {
                Ss[r0][tx * 4 + jj] = a0[jj];
                Ss[r0 + 1][tx * 4 + jj] = a1[jj];
            }
        }
        asm volatile("" ::: "memory");   // wave-internal phase fence

        // ---- phase b: bias gather + online softmax + bins (row pr) ----
        {
            int hv[8] = {h0.x, h0.y, h0.z, h0.w, h1.x, h1.y, h1.z, h1.w};
            int ev[8] = {e0.x, e0.y, e0.z, e0.w, e1.x, e1.y, e1.z, e1.w};
            float p[8];
            float tmax = -1e30f;
#pragma unroll
            for (int u = 0; u < 8; ++u) {
                float val = (Ss[pr][ps * 8 + u] + ShopS[pr][hv[u]] + SedgeS[pr][ev[u]]) * SCALE;
                p[u] = val;
                tmax = fmaxf(tmax, val);
            }
            tmax = fmaxf(tmax, __shfl_xor(tmax, 1));
            tmax = fmaxf(tmax, __shfl_xor(tmax, 2));
            tmax = fmaxf(tmax, __shfl_xor(tmax, 4));
            float m_new = fmaxf(m_run, tmax);
            float alpha = __expf(m_run - m_new);
            float psum = 0.f;
#pragma unroll
            for (int u = 0; u < 8; ++u) {
                p[u] = __expf(p[u] - m_new);
                psum += p[u];
            }
            psum += __shfl_xor(psum, 1);
            psum += __shfl_xor(psum, 2);
            psum += __shfl_xor(psum, 4);
            l_run = l_run * alpha + psum;
            m_run = m_new;
#pragma unroll
            for (int u = 0; u < 8; ++u) acc[u] *= alpha;
#pragma unroll
            for (int u = 0; u < 4; ++u) vhaS[pr][ps * 4 + u] *= alpha;
#pragma unroll
            for (int u = 0; u < 8; ++u) veaS[pr][ps * 8 + u] *= alpha;
#pragma unroll
            for (int u = 0; u < 8; ++u) Ss[pr][ps * 8 + u] = p[u];
            asm volatile("" ::: "memory");   // p + rescale visible (in-order wave LDS)
#pragma unroll
            for (int u = 0; u < 8; ++u) {
                atomicAdd(&vhaS[pr][hv[u]], p[u]);
                atomicAdd(&veaS[pr][ev[u]], p[u]);
            }
        }
        asm volatile("" ::: "memory");

        // ---- phase c: PV accumulate (row pr, d-slice ps*8..ps*8+7) ----
#pragma unroll 4
        for (int j = 0; j < 64; ++j) {
            float pj = Ss[pr][j];
            float4 v0 = *(const float4*)&Vs[j][ps * 8];
            float4 v1 = *(const float4*)&Vs[j][ps * 8 + 4];
            acc[0] += pj * v0.x; acc[1] += pj * v0.y;
            acc[2] += pj * v0.z; acc[3] += pj * v0.w;
            acc[4] += pj * v1.x; acc[5] += pj * v1.y;
            acc[6] += pj * v1.z; acc[7] += pj * v1.w;
        }
    }
    asm volatile("" ::: "memory");   // last tile's bin atomics (in-order, same wave)

    // ---- epilogue: x1 + vha@vhe + vea@vee, normalize, store (wave-local) ----
    float inv = 1.0f / l_run;
    float o[8];
#pragma unroll
    for (int u = 0; u < 8; ++u) o[u] = acc[u];
#pragma unroll 4
    for (int t = 0; t < 32; ++t) {
        float w = vhaS[pr][t];
        float4 g0 = *(const float4*)&vhe[t * 1024 + h * 64 + ps * 8];
        float4 g1 = *(const float4*)&vhe[t * 1024 + h * 64 + ps * 8 + 4];
        o[0] += w * g0.x; o[1] += w * g0.y; o[2] += w * g0.z; o[3] += w * g0.w;
        o[4] += w * g1.x; o[5] += w * g1.y; o[6] += w * g1.z; o[7] += w * g1.w;
    }
#pragma unroll 4
    for (int t = 0; t < 64; ++t) {
        float w = veaS[pr][t];
        float4 g0 = *(const float4*)&vee[t * 1024 + h * 64 + ps * 8];
        float4 g1 = *(const float4*)&vee[t * 1024 + h * 64 + ps * 8 + 4];
        o[0] += w * g0.x; o[1] += w * g0.y; o[2] += w * g0.z; o[3] += w * g0.w;
        o[4] += w * g1.x; o[5] += w * g1.y; o[6] += w * g1.z; o[7] += w * g1.w;
    }
    float* yp = Y + (b * 512 + i0 + pr) * 1024 + h * 64 + ps * 8;
    *(float4*)yp = make_float4(o[0] * inv, o[1] * inv, o[2] * inv, o[3] * inv);
    *(float4*)(yp + 4) = make_float4(o[4] * inv, o[5] * inv, o[6] * inv, o[7] * inv);
}

// ---------------------------------------------------------------------------
extern "C" void kernel_launch(void* const* d_in, const int* in_sizes, int n_in,
                              void* d_out, int out_size, void* d_ws, size_t ws_size,
                              hipStream_t stream)
{
    (void)in_sizes; (void)n_in; (void)out_size; (void)ws_size;
    const float* x   = (const float*)d_in[0];
    const float* qhe = (const float*)d_in[1];
    const float* qee = (const float*)d_in[2];
    const float* khe = (const float*)d_in[3];
    const float* kee = (const float*)d_in[4];
    const float* vhe = (const float*)d_in[5];
    const float* vee = (const float*)d_in[6];
    const int*   hop = (const int*)d_in[7];
    const int*   edg = (const int*)d_in[8];
    const float* Wq = (const float*)d_in[9];  const float* bq = (const float*)d_in[10];
    const float* Wk = (const float*)d_in[11]; const float* bk = (const float*)d_in[12];
    const float* Wv = (const float*)d_in[13]; const float* bv = (const float*)d_in[14];
    const float* Wo = (const float*)d_in[15]; const float* bo = (const float*)d_in[16];

    float* ws    = (float*)d_ws;
    float* Qb    = ws;                    // 8388608 floats
    float* Kb    = Qb + 8388608;
    float* Vb    = Kb + 8388608;
    float* Shop  = Vb + 8388608;          // 4194304
    float* Sedge = Shop + 4194304;        // 8388608
    float* Yb    = Sedge + 8388608;       // 8388608   (total 184.5 MB)

    dim3 gGemm(64, 8);
    gemm_xwT<<<gGemm, 256, 0, stream>>>(x, Wq, bq, Qb, 1);
    gemm_xwT<<<gGemm, 256, 0, stream>>>(x, Wk, bk, Kb, 1);
    gemm_xwT<<<gGemm, 256, 0, stream>>>(x, Wv, bv, Vb, 1);
    type_scores<<<2048, 256, 0, stream>>>(Qb, Kb, qhe, qee, khe, kee, Shop, Sedge);
    attn_fused<<<dim3(16, 16, 16), 256, 0, stream>>>(Qb, Kb, Vb, Shop, Sedge,
                                                     hop, edg, vhe, vee, Yb);
    gemm_xwT<<<gGemm, 256, 0, stream>>>(Yb, Wo, bo, (float*)d_out, 0);
}

// Round 4
// 1930.748 us; speedup vs baseline: 1.2011x; 1.1971x over previous
//
#include <hip/hip_runtime.h>

// Graphormer-style multi-head attention.
// B=16, N=512, HID=1024, H=16, D=64, T_HOP=32, T_EDGE=64, SCALE=1/8.
//
// R3 (resubmit — prior bench hit GPUAcquisitionTimeout, no data):
//     GEMMs -> split-bf16 MFMA (Ah+Al)(Bh+Bl) ~= AhBh+AhBl+AlBh (~fp32 acc.)
//     m97-style: 128x64 tile, BK=32, k-sliced LDS, global_load_lds(16B),
//     mfma_f32_16x16x32_bf16. attn_fused/type_scores byte-identical to R2.
//
// ws (floats): Q(8388608) K(8388608) V(8388608) Shop(4194304) Sedge(8388608)
//              Y(8388608) | xh/xl (8.4M ushort each, reused as yh/yl)
//              wh/wl (1M ushort each)   => ~222 MB total

#define SCALE 0.125f

typedef __attribute__((ext_vector_type(8))) short bf16x8;
typedef __attribute__((ext_vector_type(4))) float f32x4;

__device__ __forceinline__ ushort f2bf(float x) {
    unsigned u = __float_as_uint(x);
    return (ushort)((u + 0x7FFF + ((u >> 16) & 1)) >> 16);
}
__device__ __forceinline__ float bf2f(ushort h) {
    return __uint_as_float(((unsigned)h) << 16);
}

__device__ __forceinline__ void stage16(const ushort* g, ushort* l) {
#if defined(__has_builtin) && __has_builtin(__builtin_amdgcn_global_load_lds)
    __builtin_amdgcn_global_load_lds(
        (const __attribute__((address_space(1))) unsigned int*)g,
        (__attribute__((address_space(3))) unsigned int*)l, 16, 0, 0);
#else
    typedef __attribute__((ext_vector_type(8))) unsigned short u16x8;
    *(u16x8*)l = *(const u16x8*)g;
#endif
}

// ---------------------------------------------------------------------------
// split fp32 -> bf16 hi + bf16 lo (residual), RN.  n % 4 == 0.
// ---------------------------------------------------------------------------
__global__ __launch_bounds__(256) void split_bf16(
    const float* __restrict__ in, ushort* __restrict__ oh,
    ushort* __restrict__ ol, int n)
{
    const int stride = gridDim.x * 256 * 4;
    for (int i = (blockIdx.x * 256 + threadIdx.x) * 4; i < n; i += stride) {
        float4 v = *(const float4*)&in[i];
        ushort4 h, l;
        h.x = f2bf(v.x); l.x = f2bf(v.x - bf2f(h.x));
        h.y = f2bf(v.y); l.y = f2bf(v.y - bf2f(h.y));
        h.z = f2bf(v.z); l.z = f2bf(v.z - bf2f(h.z));
        h.w = f2bf(v.w); l.w = f2bf(v.w - bf2f(h.w));
        *(ushort4*)&oh[i] = h;
        *(ushort4*)&ol[i] = l;
    }
}

// ---------------------------------------------------------------------------
// MFMA GEMM: C = (Ah+Al) @ (Bh+Bl)^T + bias, fp32 out.
// A:[8192,1024] bf16 hi/lo, B(=W):[1024,1024] bf16 hi/lo (row n holds k-dim).
// Tile 128(m) x 64(n), BK=32. 256 thr = 4 waves, wave quadrant 64x32.
// LDS k-sliced [koff][row][8] so global_load_lds dest is linear base+lane*16
// and frag ds_read_b128 is bank-uniform (2-way = free).
// layout==0: C[m*1024+n]; layout==1: QKV ((b*16+h)*512+i)*64+d.
// ---------------------------------------------------------------------------
__global__ __launch_bounds__(256) void gemm_mfma(
    const ushort* __restrict__ Ah, const ushort* __restrict__ Al,
    const ushort* __restrict__ Bh, const ushort* __restrict__ Bl,
    const float* __restrict__ bias, float* __restrict__ C, int layout)
{
    __shared__ ushort sAh[4096];   // 4 koff x 128 row x 8
    __shared__ ushort sAl[4096];
    __shared__ ushort sBh[2048];   // 4 koff x 64 n x 8
    __shared__ ushort sBl[2048];

    const int tid = threadIdx.x;
    const int m0 = blockIdx.x * 128, n0 = blockIdx.y * 64;
    const int l = tid & 63, w = tid >> 6;
    const int wr = w >> 1, wc = w & 1;       // wave quadrant (64 rows x 32 cols)
    const int koff = l >> 4, r16 = l & 15;

    f32x4 acc[4][2] = {};

    // staging slots: A has 512 slots (2/thread), B has 256 (1/thread)
    const int sa0 = tid, sa1 = tid + 256;
    const int ar0 = sa0 & 127, ak0 = sa0 >> 7;
    const int ar1 = sa1 & 127, ak1 = sa1 >> 7;
    const int bn = tid & 63, bk = tid >> 6;

    const ushort* gAh0 = Ah + (size_t)(m0 + ar0) * 1024 + ak0 * 8;
    const ushort* gAh1 = Ah + (size_t)(m0 + ar1) * 1024 + ak1 * 8;
    const ushort* gAl0 = Al + (size_t)(m0 + ar0) * 1024 + ak0 * 8;
    const ushort* gAl1 = Al + (size_t)(m0 + ar1) * 1024 + ak1 * 8;
    const ushort* gBh0 = Bh + (size_t)(n0 + bn) * 1024 + bk * 8;
    const ushort* gBl0 = Bl + (size_t)(n0 + bn) * 1024 + bk * 8;

    for (int kt = 0; kt < 32; ++kt) {
        const int k0 = kt * 32;
        __syncthreads();                      // done reading previous tile
        stage16(gAh0 + k0, &sAh[sa0 * 8]);
        stage16(gAh1 + k0, &sAh[sa1 * 8]);
        stage16(gAl0 + k0, &sAl[sa0 * 8]);
        stage16(gAl1 + k0, &sAl[sa1 * 8]);
        stage16(gBh0 + k0, &sBh[tid * 8]);
        stage16(gBl0 + k0, &sBl[tid * 8]);
        __syncthreads();                      // vmcnt(0) drained by compiler

        bf16x8 fah[4], fal[4], fbh[2], fbl[2];
#pragma unroll
        for (int mi = 0; mi < 4; ++mi) {
            const int off = (koff * 128 + wr * 64 + mi * 16 + r16) * 8;
            fah[mi] = *(const bf16x8*)&sAh[off];
            fal[mi] = *(const bf16x8*)&sAl[off];
        }
#pragma unroll
        for (int ni = 0; ni < 2; ++ni) {
            const int off = (koff * 64 + wc * 32 + ni * 16 + r16) * 8;
            fbh[ni] = *(const bf16x8*)&sBh[off];
            fbl[ni] = *(const bf16x8*)&sBl[off];
        }
#pragma unroll
        for (int mi = 0; mi < 4; ++mi)
#pragma unroll
            for (int ni = 0; ni < 2; ++ni) {
                acc[mi][ni] = __builtin_amdgcn_mfma_f32_16x16x32_bf16(
                    fah[mi], fbh[ni], acc[mi][ni], 0, 0, 0);
                acc[mi][ni] = __builtin_amdgcn_mfma_f32_16x16x32_bf16(
                    fah[mi], fbl[ni], acc[mi][ni], 0, 0, 0);
                acc[mi][ni] = __builtin_amdgcn_mfma_f32_16x16x32_bf16(
                    fal[mi], fbh[ni], acc[mi][ni], 0, 0, 0);
            }
    }

    // epilogue: D col = lane&15, row = (lane>>4)*4 + reg
#pragma unroll
    for (int mi = 0; mi < 4; ++mi) {
        const int rowb = m0 + wr * 64 + mi * 16 + (l >> 4) * 4;
#pragma unroll
        for (int ni = 0; ni < 2; ++ni) {
            const int col = n0 + wc * 32 + ni * 16 + (l & 15);
            const float bb = bias[col];
#pragma unroll
            for (int r = 0; r < 4; ++r) {
                const int m = rowb + r;
                const float v = acc[mi][ni][r] + bb;
                if (layout == 0) {
                    C[(size_t)m * 1024 + col] = v;
                } else {
                    const int b16 = m >> 9, i2 = m & 511;
                    const int hh = col >> 6, dd = col & 63;
                    C[((size_t)(b16 * 16 + hh) * 512 + i2) * 64 + dd] = v;
                }
            }
        }
    }
}

// ---------------------------------------------------------------------------
// Type scores (unchanged from R2).
// ---------------------------------------------------------------------------
__global__ __launch_bounds__(256) void type_scores(
    const float* __restrict__ Q, const float* __restrict__ K,
    const float* __restrict__ qhe, const float* __restrict__ qee,
    const float* __restrict__ khe, const float* __restrict__ kee,
    float* __restrict__ Shop, float* __restrict__ Sedge)
{
    __shared__ float qs[64][65];
    __shared__ float ks[64][65];
    const int tid = threadIdx.x;
    const int i0 = (blockIdx.x & 7) * 64;
    const int bh = blockIdx.x >> 3;
    const int h = bh & 15;
    {
        const int r = tid >> 2, c16 = (tid & 3) << 4;
        const float* qp = Q + (bh * 512 + i0 + r) * 64 + c16;
        const float* kp = K + (bh * 512 + i0 + r) * 64 + c16;
#pragma unroll
        for (int u = 0; u < 4; ++u) {
            float4 q4 = *(const float4*)(qp + u * 4);
            float4 k4 = *(const float4*)(kp + u * 4);
            qs[r][c16 + u * 4 + 0] = q4.x; qs[r][c16 + u * 4 + 1] = q4.y;
            qs[r][c16 + u * 4 + 2] = q4.z; qs[r][c16 + u * 4 + 3] = q4.w;
            ks[r][c16 + u * 4 + 0] = k4.x; ks[r][c16 + u * 4 + 1] = k4.y;
            ks[r][c16 + u * 4 + 2] = k4.z; ks[r][c16 + u * 4 + 3] = k4.w;
        }
    }
    __syncthreads();
    const int i = tid & 63;
    const int tq = tid >> 6;
    for (int tt = 0; tt < 24; ++tt) {
        int t96 = tq * 24 + tt;
        const float *eq, *ek;
        float* outp;
        if (t96 < 32) {
            eq = qhe + t96 * 1024 + h * 64;
            ek = khe + t96 * 1024 + h * 64;
            outp = &Shop[(bh * 512 + i0 + i) * 32 + t96];
        } else {
            int t = t96 - 32;
            eq = qee + t * 1024 + h * 64;
            ek = kee + t * 1024 + h * 64;
            outp = &Sedge[(bh * 512 + i0 + i) * 64 + t];
        }
        float s0 = 0.f, s1 = 0.f, s2 = 0.f, s3 = 0.f;
#pragma unroll 4
        for (int d = 0; d < 64; d += 4) {
            s0 += qs[i][d + 0] * eq[d + 0] + ks[i][d + 0] * ek[d + 0];
            s1 += qs[i][d + 1] * eq[d + 1] + ks[i][d + 1] * ek[d + 1];
            s2 += qs[i][d + 2] * eq[d + 2] + ks[i][d + 2] * ek[d + 2];
            s3 += qs[i][d + 3] * eq[d + 3] + ks[i][d + 3] * ek[d + 3];
        }
        *outp = (s0 + s1) + (s2 + s3);
    }
}

// ---------------------------------------------------------------------------
// Fused attention (unchanged from R2).
// ---------------------------------------------------------------------------
__global__ __launch_bounds__(256) void attn_fused(
    const float* __restrict__ Qg, const float* __restrict__ Kg,
    const float* __restrict__ Vg,
    const float* __restrict__ Shop, const float* __restrict__ Sedge,
    const int* __restrict__ hop, const int* __restrict__ edge,
    const float* __restrict__ vhe, const float* __restrict__ vee,
    float* __restrict__ Y)
{
    __shared__ float qs[64][36];      // [d][i]
    __shared__ float Ks[64][68];      // [d][j]
    __shared__ float Vs[64][68];      // [j][d]
    __shared__ float Ss[32][65];      // [i][j]
    __shared__ float ShopS[32][33];
    __shared__ float SedgeS[32][65];
    __shared__ float vhaS[32][33];
    __shared__ float veaS[32][65];

    const int tid = threadIdx.x;
    const int i0 = blockIdx.x * 32;
    const int h = blockIdx.y;
    const int b = blockIdx.z;
    const int bh = b * 16 + h;

    const int pr = tid >> 3;
    const int ps = tid & 7;
    const int tx = tid & 15;
    const int r0 = (tid >> 4) * 2;

    {
        const float* qp = Qg + (bh * 512 + i0 + pr) * 64 + ps * 8;
        float4 q0 = *(const float4*)qp;
        float4 q1 = *(const float4*)(qp + 4);
        qs[ps * 8 + 0][pr] = q0.x; qs[ps * 8 + 1][pr] = q0.y;
        qs[ps * 8 + 2][pr] = q0.z; qs[ps * 8 + 3][pr] = q0.w;
        qs[ps * 8 + 4][pr] = q1.x; qs[ps * 8 + 5][pr] = q1.y;
        qs[ps * 8 + 6][pr] = q1.z; qs[ps * 8 + 7][pr] = q1.w;

        float4 sh = *(const float4*)&Shop[(bh * 512 + i0 + pr) * 32 + ps * 4];
        ShopS[pr][ps * 4 + 0] = sh.x; ShopS[pr][ps * 4 + 1] = sh.y;
        ShopS[pr][ps * 4 + 2] = sh.z; ShopS[pr][ps * 4 + 3] = sh.w;
        float4 se0 = *(const float4*)&Sedge[(bh * 512 + i0 + pr) * 64 + ps * 8];
        float4 se1 = *(const float4*)&Sedge[(bh * 512 + i0 + pr) * 64 + ps * 8 + 4];
        SedgeS[pr][ps * 8 + 0] = se0.x; SedgeS[pr][ps * 8 + 1] = se0.y;
        SedgeS[pr][ps * 8 + 2] = se0.z; SedgeS[pr][ps * 8 + 3] = se0.w;
        SedgeS[pr][ps * 8 + 4] = se1.x; SedgeS[pr][ps * 8 + 5] = se1.y;
        SedgeS[pr][ps * 8 + 6] = se1.z; SedgeS[pr][ps * 8 + 7] = se1.w;

#pragma unroll
        for (int u = 0; u < 4; ++u) vhaS[pr][ps * 4 + u] = 0.f;
#pragma unroll
        for (int u = 0; u < 8; ++u) veaS[pr][ps * 8 + u] = 0.f;
    }

    float m_run = -1e30f, l_run = 0.f;
    float acc[8];
#pragma unroll
    for (int u = 0; u < 8; ++u) acc[u] = 0.f;

    const int lr = tid >> 2;
    const int lq = tid & 3;

    float4 kv[4], vv[4];
    {
        const float* Kp = Kg + (bh * 512 + lr) * 64;
        const float* Vp = Vg + (bh * 512 + lr) * 64;
#pragma unroll
        for (int u = 0; u < 4; ++u) {
            kv[u] = *(const float4*)(Kp + lq * 4 + u * 16);
            vv[u] = *(const float4*)(Vp + lq * 4 + u * 16);
        }
    }

    for (int t = 0; t < 8; ++t) {
        const int j0 = t * 64;
        __syncthreads();
#pragma unroll
        for (int u = 0; u < 4; ++u) {
            int d = lq * 4 + u * 16;
            Ks[d + 0][lr] = kv[u].x; Ks[d + 1][lr] = kv[u].y;
            Ks[d + 2][lr] = kv[u].z; Ks[d + 3][lr] = kv[u].w;
            *(float4*)&Vs[lr][d] = vv[u];
        }
        __syncthreads();

        {
            int jn = (t < 7) ? (j0 + 64) : 0;
            const float* Kp = Kg + (bh * 512 + jn + lr) * 64;
            const float* Vp = Vg + (bh * 512 + jn + lr) * 64;
#pragma unroll
            for (int u = 0; u < 4; ++u) {
                kv[u] = *(const float4*)(Kp + lq * 4 + u * 16);
                vv[u] = *(const float4*)(Vp + lq * 4 + u * 16);
            }
        }
        const int* hp = hop + (b * 512 + i0 + pr) * 512 + j0 + ps * 8;
        const int* ep = edge + (b * 512 + i0 + pr) * 512 + j0 + ps * 8;
        int4 h0 = *(const int4*)hp, h1 = *(const int4*)(hp + 4);
        int4 e0 = *(const int4*)ep, e1 = *(const int4*)(ep + 4);

        {
            float a0[4] = {0.f, 0.f, 0.f, 0.f};
            float a1[4] = {0.f, 0.f, 0.f, 0.f};
#pragma unroll 8
            for (int d = 0; d < 64; ++d) {
                float2 aa = *(const float2*)&qs[d][r0];
                float4 bb = *(const float4*)&Ks[d][tx * 4];
                a0[0] += aa.x * bb.x; a0[1] += aa.x * bb.y;
                a0[2] += aa.x * bb.z; a0[3] += aa.x * bb.w;
                a1[0] += aa.y * bb.x; a1[1] += aa.y * bb.y;
                a1[2] += aa.y * bb.z; a1[3] += aa.y * bb.w;
            }
#pragma unroll
            for (int jj = 0; jj < 4; ++jj) {
                Ss[r0][tx * 4 + jj] = a0[jj];
                Ss[r0 + 1][tx * 4 + jj] = a1[jj];
            }
        }
        asm volatile("" ::: "memory");

        {
            int hv[8] = {h0.x, h0.y, h0.z, h0.w, h1.x, h1.y, h1.z, h1.w};
            int ev[8] = {e0.x, e0.y, e0.z, e0.w, e1.x, e1.y, e1.z, e1.w};
            float p[8];
            float tmax = -1e30f;
#pragma unroll
            for (int u = 0; u < 8; ++u) {
                float val = (Ss[pr][ps * 8 + u] + ShopS[pr][hv[u]] + SedgeS[pr][ev[u]]) * SCALE;
                p[u] = val;
                tmax = fmaxf(tmax, val);
            }
            tmax = fmaxf(tmax, __shfl_xor(tmax, 1));
            tmax = fmaxf(tmax, __shfl_xor(tmax, 2));
            tmax = fmaxf(tmax, __shfl_xor(tmax, 4));
            float m_new = fmaxf(m_run, tmax);
            float alpha = __expf(m_run - m_new);
            float psum = 0.f;
#pragma unroll
            for (int u = 0; u < 8; ++u) {
                p[u] = __expf(p[u] - m_new);
                psum += p[u];
            }
            psum += __shfl_xor(psum, 1);
            psum += __shfl_xor(psum, 2);
            psum += __shfl_xor(psum, 4);
            l_run = l_run * alpha + psum;
            m_run = m_new;
#pragma unroll
            for (int u = 0; u < 8; ++u) acc[u] *= alpha;
#pragma unroll
            for (int u = 0; u < 4; ++u) vhaS[pr][ps * 4 + u] *= alpha;
#pragma unroll
            for (int u = 0; u < 8; ++u) veaS[pr][ps * 8 + u] *= alpha;
#pragma unroll
            for (int u = 0; u < 8; ++u) Ss[pr][ps * 8 + u] = p[u];
            asm volatile("" ::: "memory");
#pragma unroll
            for (int u = 0; u < 8; ++u) {
                atomicAdd(&vhaS[pr][hv[u]], p[u]);
                atomicAdd(&veaS[pr][ev[u]], p[u]);
            }
        }
        asm volatile("" ::: "memory");

#pragma unroll 4
        for (int j = 0; j < 64; ++j) {
            float pj = Ss[pr][j];
            float4 v0 = *(const float4*)&Vs[j][ps * 8];
            float4 v1 = *(const float4*)&Vs[j][ps * 8 + 4];
            acc[0] += pj * v0.x; acc[1] += pj * v0.y;
            acc[2] += pj * v0.z; acc[3] += pj * v0.w;
            acc[4] += pj * v1.x; acc[5] += pj * v1.y;
            acc[6] += pj * v1.z; acc[7] += pj * v1.w;
        }
    }
    asm volatile("" ::: "memory");

    float inv = 1.0f / l_run;
    float o[8];
#pragma unroll
    for (int u = 0; u < 8; ++u) o[u] = acc[u];
#pragma unroll 4
    for (int t = 0; t < 32; ++t) {
        float w = vhaS[pr][t];
        float4 g0 = *(const float4*)&vhe[t * 1024 + h * 64 + ps * 8];
        float4 g1 = *(const float4*)&vhe[t * 1024 + h * 64 + ps * 8 + 4];
        o[0] += w * g0.x; o[1] += w * g0.y; o[2] += w * g0.z; o[3] += w * g0.w;
        o[4] += w * g1.x; o[5] += w * g1.y; o[6] += w * g1.z; o[7] += w * g1.w;
    }
#pragma unroll 4
    for (int t = 0; t < 64; ++t) {
        float w = veaS[pr][t];
        float4 g0 = *(const float4*)&vee[t * 1024 + h * 64 + ps * 8];
        float4 g1 = *(const float4*)&vee[t * 1024 + h * 64 + ps * 8 + 4];
        o[0] += w * g0.x; o[1] += w * g0.y; o[2] += w * g0.z; o[3] += w * g0.w;
        o[4] += w * g1.x; o[5] += w * g1.y; o[6] += w * g1.z; o[7] += w * g1.w;
    }
    float* yp = Y + (b * 512 + i0 + pr) * 1024 + h * 64 + ps * 8;
    *(float4*)yp = make_float4(o[0] * inv, o[1] * inv, o[2] * inv, o[3] * inv);
    *(float4*)(yp + 4) = make_float4(o[4] * inv, o[5] * inv, o[6] * inv, o[7] * inv);
}

// ---------------------------------------------------------------------------
extern "C" void kernel_launch(void* const* d_in, const int* in_sizes, int n_in,
                              void* d_out, int out_size, void* d_ws, size_t ws_size,
                              hipStream_t stream)
{
    (void)in_sizes; (void)n_in; (void)out_size; (void)ws_size;
    const float* x   = (const float*)d_in[0];
    const float* qhe = (const float*)d_in[1];
    const float* qee = (const float*)d_in[2];
    const float* khe = (const float*)d_in[3];
    const float* kee = (const float*)d_in[4];
    const float* vhe = (const float*)d_in[5];
    const float* vee = (const float*)d_in[6];
    const int*   hop = (const int*)d_in[7];
    const int*   edg = (const int*)d_in[8];
    const float* Wq = (const float*)d_in[9];  const float* bq = (const float*)d_in[10];
    const float* Wk = (const float*)d_in[11]; const float* bk = (const float*)d_in[12];
    const float* Wv = (const float*)d_in[13]; const float* bv = (const float*)d_in[14];
    const float* Wo = (const float*)d_in[15]; const float* bo = (const float*)d_in[16];

    float* ws    = (float*)d_ws;
    float* Qb    = ws;
    float* Kb    = Qb + 8388608;
    float* Vb    = Kb + 8388608;
    float* Shop  = Vb + 8388608;          // 4194304
    float* Sedge = Shop + 4194304;        // 8388608
    float* Yb    = Sedge + 8388608;       // 8388608  (fp32 region: 184.5 MB)
    ushort* xh   = (ushort*)(Yb + 8388608);   // 8388608 ushort (= yh later)
    ushort* xl   = xh + 8388608;              // 8388608 ushort (= yl later)
    ushort* wh   = xl + 8388608;              // 1048576 ushort
    ushort* wl   = wh + 1048576;              // 1048576 ushort  (~222 MB total)

    const dim3 gG(64, 16);   // 8192/128 x 1024/64

    split_bf16<<<2048, 256, 0, stream>>>(x, xh, xl, 8388608);
    split_bf16<<<512, 256, 0, stream>>>(Wq, wh, wl, 1048576);
    gemm_mfma<<<gG, 256, 0, stream>>>(xh, xl, wh, wl, bq, Qb, 1);
    split_bf16<<<512, 256, 0, stream>>>(Wk, wh, wl, 1048576);
    gemm_mfma<<<gG, 256, 0, stream>>>(xh, xl, wh, wl, bk, Kb, 1);
    split_bf16<<<512, 256, 0, stream>>>(Wv, wh, wl, 1048576);
    gemm_mfma<<<gG, 256, 0, stream>>>(xh, xl, wh, wl, bv, Vb, 1);

    type_scores<<<2048, 256, 0, stream>>>(Qb, Kb, qhe, qee, khe, kee, Shop, Sedge);
    attn_fused<<<dim3(16, 16, 16), 256, 0, stream>>>(Qb, Kb, Vb, Shop, Sedge,
                                                     hop, edg, vhe, vee, Yb);

    split_bf16<<<2048, 256, 0, stream>>>(Yb, xh, xl, 8388608);   // reuse as yh/yl
    split_bf16<<<512, 256, 0, stream>>>(Wo, wh, wl, 1048576);
    gemm_mfma<<<gG, 256, 0, stream>>>(xh, xl, wh, wl, bo, (float*)d_out, 0);
}

// Round 5
// 1543.447 us; speedup vs baseline: 1.5025x; 1.2509x over previous
//
#include <hip/hip_runtime.h>

// Graphormer-style multi-head attention.
// B=16, N=512, HID=1024, H=16, D=64, T_HOP=32, T_EDGE=64, SCALE=1/8.
//
// R5: attention core -> MFMA.
//  - QKV gemms write bf16 hi/lo (Q,K) and transposed single-bf16 V^T [bh][d][j]
//  - attn_mfma: per (b,h,i-tile-of-64), 4 waves x 16 q-rows. QK^T = split-bf16
//    (3 mfma), PV = single-bf16 (1 mfma). K/V staged via global_load_lds with
//    XOR-swizzled source; P round-trips through swizzled LDS (D-layout ->
//    A-layout). Softmax in 16-lane groups; defer-max (THR=10) makes rescale
//    a rare path. Bins wave-private in LDS. 2 barriers/tile.
//  - type_scores consumes hi/lo, writes bf16 bias tables.
//
// ws: Qh Ql Kh Kl Vt (5 x 8388608 u16) ShopB(4194304 u16) SedgeB(8388608 u16)
//     Yb(8388608 f32) xh xl (8388608 u16) wh wl (1048576 u16)  => ~180 MB

#define SCALE 0.125f

typedef __attribute__((ext_vector_type(8))) short bf16x8;
typedef __attribute__((ext_vector_type(4))) float f32x4;

__device__ __forceinline__ ushort f2bf(float x) {
    unsigned u = __float_as_uint(x);
    return (ushort)((u + 0x7FFF + ((u >> 16) & 1)) >> 16);
}
__device__ __forceinline__ float bf2f(ushort h) {
    return __uint_as_float(((unsigned)h) << 16);
}

__device__ __forceinline__ void stage16(const ushort* g, ushort* l) {
    __builtin_amdgcn_global_load_lds(
        (const __attribute__((address_space(1))) unsigned int*)g,
        (__attribute__((address_space(3))) unsigned int*)l, 16, 0, 0);
}

// ---------------------------------------------------------------------------
// split fp32 -> bf16 hi + lo residual
// ---------------------------------------------------------------------------
__global__ __launch_bounds__(256) void split_bf16(
    const float* __restrict__ in, ushort* __restrict__ oh,
    ushort* __restrict__ ol, int n)
{
    const int stride = gridDim.x * 256 * 4;
    for (int i = (blockIdx.x * 256 + threadIdx.x) * 4; i < n; i += stride) {
        float4 v = *(const float4*)&in[i];
        ushort4 h, l;
        h.x = f2bf(v.x); l.x = f2bf(v.x - bf2f(h.x));
        h.y = f2bf(v.y); l.y = f2bf(v.y - bf2f(h.y));
        h.z = f2bf(v.z); l.z = f2bf(v.z - bf2f(h.z));
        h.w = f2bf(v.w); l.w = f2bf(v.w - bf2f(h.w));
        *(ushort4*)&oh[i] = h;
        *(ushort4*)&ol[i] = l;
    }
}

// ---------------------------------------------------------------------------
// MFMA GEMM: C = (Ah+Al)@(Bh+Bl)^T + bias.
// layout 0: Cf[m*1024+n] fp32
// layout 1: Ch/Cl bf16 hi/lo at ((b*16+h)*512+i)*64+d   (Q, K)
// layout 2: Ch bf16 V^T at ((b*16+h)*64+d)*512+i        (V)
// ---------------------------------------------------------------------------
__global__ __launch_bounds__(256) void gemm_mfma(
    const ushort* __restrict__ Ah, const ushort* __restrict__ Al,
    const ushort* __restrict__ Bh, const ushort* __restrict__ Bl,
    const float* __restrict__ bias, float* __restrict__ Cf,
    ushort* __restrict__ Ch, ushort* __restrict__ Cl, int layout)
{
    __shared__ ushort sAh[4096];
    __shared__ ushort sAl[4096];
    __shared__ ushort sBh[2048];
    __shared__ ushort sBl[2048];

    const int tid = threadIdx.x;
    const int m0 = blockIdx.x * 128, n0 = blockIdx.y * 64;
    const int l = tid & 63, w = tid >> 6;
    const int wr = w >> 1, wc = w & 1;
    const int koff = l >> 4, r16 = l & 15;

    f32x4 acc[4][2] = {};

    const int sa0 = tid, sa1 = tid + 256;
    const int ar0 = sa0 & 127, ak0 = sa0 >> 7;
    const int ar1 = sa1 & 127, ak1 = sa1 >> 7;
    const int bn = tid & 63, bk = tid >> 6;

    const ushort* gAh0 = Ah + (size_t)(m0 + ar0) * 1024 + ak0 * 8;
    const ushort* gAh1 = Ah + (size_t)(m0 + ar1) * 1024 + ak1 * 8;
    const ushort* gAl0 = Al + (size_t)(m0 + ar0) * 1024 + ak0 * 8;
    const ushort* gAl1 = Al + (size_t)(m0 + ar1) * 1024 + ak1 * 8;
    const ushort* gBh0 = Bh + (size_t)(n0 + bn) * 1024 + bk * 8;
    const ushort* gBl0 = Bl + (size_t)(n0 + bn) * 1024 + bk * 8;

    for (int kt = 0; kt < 32; ++kt) {
        const int k0 = kt * 32;
        __syncthreads();
        stage16(gAh0 + k0, &sAh[sa0 * 8]);
        stage16(gAh1 + k0, &sAh[sa1 * 8]);
        stage16(gAl0 + k0, &sAl[sa0 * 8]);
        stage16(gAl1 + k0, &sAl[sa1 * 8]);
        stage16(gBh0 + k0, &sBh[tid * 8]);
        stage16(gBl0 + k0, &sBl[tid * 8]);
        __syncthreads();

        bf16x8 fah[4], fal[4], fbh[2], fbl[2];
#pragma unroll
        for (int mi = 0; mi < 4; ++mi) {
            const int off = (koff * 128 + wr * 64 + mi * 16 + r16) * 8;
            fah[mi] = *(const bf16x8*)&sAh[off];
            fal[mi] = *(const bf16x8*)&sAl[off];
        }
#pragma unroll
        for (int ni = 0; ni < 2; ++ni) {
            const int off = (koff * 64 + wc * 32 + ni * 16 + r16) * 8;
            fbh[ni] = *(const bf16x8*)&sBh[off];
            fbl[ni] = *(const bf16x8*)&sBl[off];
        }
#pragma unroll
        for (int mi = 0; mi < 4; ++mi)
#pragma unroll
            for (int ni = 0; ni < 2; ++ni) {
                acc[mi][ni] = __builtin_amdgcn_mfma_f32_16x16x32_bf16(
                    fah[mi], fbh[ni], acc[mi][ni], 0, 0, 0);
                acc[mi][ni] = __builtin_amdgcn_mfma_f32_16x16x32_bf16(
                    fah[mi], fbl[ni], acc[mi][ni], 0, 0, 0);
                acc[mi][ni] = __builtin_amdgcn_mfma_f32_16x16x32_bf16(
                    fal[mi], fbh[ni], acc[mi][ni], 0, 0, 0);
            }
    }

#pragma unroll
    for (int mi = 0; mi < 4; ++mi) {
        const int rowb = m0 + wr * 64 + mi * 16 + (l >> 4) * 4;
#pragma unroll
        for (int ni = 0; ni < 2; ++ni) {
            const int col = n0 + wc * 32 + ni * 16 + (l & 15);
            const float bb = bias[col];
            float v[4];
#pragma unroll
            for (int r = 0; r < 4; ++r) v[r] = acc[mi][ni][r] + bb;
            if (layout == 0) {
#pragma unroll
                for (int r = 0; r < 4; ++r)
                    Cf[(size_t)(rowb + r) * 1024 + col] = v[r];
            } else if (layout == 1) {
                const int b16_ = rowb >> 9, i2 = rowb & 511;
                const int hh = col >> 6, dd = col & 63;
                const size_t base = ((size_t)(b16_ * 16 + hh) * 512 + i2) * 64 + dd;
#pragma unroll
                for (int r = 0; r < 4; ++r) {
                    ushort hv_ = f2bf(v[r]);
                    Ch[base + (size_t)r * 64] = hv_;
                    Cl[base + (size_t)r * 64] = f2bf(v[r] - bf2f(hv_));
                }
            } else {
                const int b16_ = rowb >> 9, i2 = rowb & 511;
                const int hh = col >> 6, dd = col & 63;
                ushort4 pk;
                pk.x = f2bf(v[0]); pk.y = f2bf(v[1]);
                pk.z = f2bf(v[2]); pk.w = f2bf(v[3]);
                *(ushort4*)&Ch[((size_t)(b16_ * 16 + hh) * 64 + dd) * 512 + i2] = pk;
            }
        }
    }
}

// ---------------------------------------------------------------------------
// Type scores from hi/lo Q,K; writes bf16 bias tables.
// ---------------------------------------------------------------------------
__global__ __launch_bounds__(256) void type_scores(
    const ushort* __restrict__ Qh, const ushort* __restrict__ Ql,
    const ushort* __restrict__ Kh, const ushort* __restrict__ Kl,
    const float* __restrict__ qhe, const float* __restrict__ qee,
    const float* __restrict__ khe, const float* __restrict__ kee,
    ushort* __restrict__ Shop, ushort* __restrict__ Sedge)
{
    __shared__ float qs[64][65];
    __shared__ float ks[64][65];
    const int tid = threadIdx.x;
    const int i0 = (blockIdx.x & 7) * 64;
    const int bh = blockIdx.x >> 3;
    const int h = bh & 15;
    {
        const int r = tid >> 2, c16 = (tid & 3) << 4;
        const size_t off = ((size_t)bh * 512 + i0 + r) * 64 + c16;
        ushort tqh[16], tql[16], tkh[16], tkl[16];
        *(uint4*)&tqh[0] = *(const uint4*)&Qh[off];
        *(uint4*)&tqh[8] = *(const uint4*)&Qh[off + 8];
        *(uint4*)&tql[0] = *(const uint4*)&Ql[off];
        *(uint4*)&tql[8] = *(const uint4*)&Ql[off + 8];
        *(uint4*)&tkh[0] = *(const uint4*)&Kh[off];
        *(uint4*)&tkh[8] = *(const uint4*)&Kh[off + 8];
        *(uint4*)&tkl[0] = *(const uint4*)&Kl[off];
        *(uint4*)&tkl[8] = *(const uint4*)&Kl[off + 8];
#pragma unroll
        for (int u = 0; u < 16; ++u) {
            qs[r][c16 + u] = bf2f(tqh[u]) + bf2f(tql[u]);
            ks[r][c16 + u] = bf2f(tkh[u]) + bf2f(tkl[u]);
        }
    }
    __syncthreads();
    const int i = tid & 63;
    const int tq = tid >> 6;
    for (int tt = 0; tt < 24; ++tt) {
        int t96 = tq * 24 + tt;
        const float *eq, *ek;
        ushort* outp;
        if (t96 < 32) {
            eq = qhe + t96 * 1024 + h * 64;
            ek = khe + t96 * 1024 + h * 64;
            outp = &Shop[((size_t)bh * 512 + i0 + i) * 32 + t96];
        } else {
            int t = t96 - 32;
            eq = qee + t * 1024 + h * 64;
            ek = kee + t * 1024 + h * 64;
            outp = &Sedge[((size_t)bh * 512 + i0 + i) * 64 + t];
        }
        float s0 = 0.f, s1 = 0.f, s2 = 0.f, s3 = 0.f;
#pragma unroll 4
        for (int d = 0; d < 64; d += 4) {
            s0 += qs[i][d + 0] * eq[d + 0] + ks[i][d + 0] * ek[d + 0];
            s1 += qs[i][d + 1] * eq[d + 1] + ks[i][d + 1] * ek[d + 1];
            s2 += qs[i][d + 2] * eq[d + 2] + ks[i][d + 2] * ek[d + 2];
            s3 += qs[i][d + 3] * eq[d + 3] + ks[i][d + 3] * ek[d + 3];
        }
        *outp = f2bf((s0 + s1) + (s2 + s3));
    }
}

// ---------------------------------------------------------------------------
// MFMA fused attention. Block = (b,h, 64 q-rows), 256 thr = 4 waves x 16 rows.
// ---------------------------------------------------------------------------
__global__ __launch_bounds__(256) void attn_mfma(
    const ushort* __restrict__ Qh, const ushort* __restrict__ Ql,
    const ushort* __restrict__ Kh, const ushort* __restrict__ Kl,
    const ushort* __restrict__ Vtb,
    const ushort* __restrict__ ShopB, const ushort* __restrict__ SedgeB,
    const int* __restrict__ hop, const int* __restrict__ edge,
    const float* __restrict__ vhe, const float* __restrict__ vee,
    float* __restrict__ Y)
{
    __shared__ ushort sKh[4096];     // 64 j x 64 d bf16, 128B rows, XOR-swizzled
    __shared__ ushort sKl[4096];
    __shared__ ushort sVt[4096];     // 64 d x 64 j bf16, swizzled
    __shared__ ushort sP[4096];      // 4 waves x 16 x 64 bf16, swizzled
    __shared__ ushort sShop[2048];   // 64 x 32 bf16
    __shared__ ushort sSedge[4096];  // 64 x 64 bf16
    __shared__ float vha[2112];      // 64 x 33
    __shared__ float vea[4160];      // 64 x 65

    const int tid = threadIdx.x;
    const int bid = blockIdx.x;
    const int swz = (bid & 7) * 256 + (bid >> 3);   // XCD-contiguous bh
    const int it = swz & 7, h = (swz >> 3) & 15, b = swz >> 7;
    const int bh = b * 16 + h;
    const int i0 = it * 64;

    const int l = tid & 63, w = tid >> 6;
    const int l15 = l & 15, lhi = l >> 4;
    const int xorv = (l15 & 7) << 4;

    // prologue: bias tables -> LDS, zero bins
    {
        const ushort* sh = ShopB + ((size_t)bh * 512 + i0) * 32 + tid * 8;
        *(uint4*)&sShop[tid * 8] = *(const uint4*)sh;
        const ushort* se = SedgeB + ((size_t)bh * 512 + i0) * 64 + tid * 16;
        *(uint4*)&sSedge[tid * 16] = *(const uint4*)se;
        *(uint4*)&sSedge[tid * 16 + 8] = *(const uint4*)(se + 8);
    }
    for (int i = tid; i < 2112; i += 256) vha[i] = 0.f;
    for (int i = tid; i < 4160; i += 256) vea[i] = 0.f;

    // Q fragments (rows i0 + w*16 + l15)
    bf16x8 qfh[2], qfl[2];
    {
        const size_t q0 = ((size_t)bh * 512 + i0 + w * 16 + l15) * 64 + lhi * 8;
        qfh[0] = *(const bf16x8*)&Qh[q0];
        qfh[1] = *(const bf16x8*)&Qh[q0 + 32];
        qfl[0] = *(const bf16x8*)&Ql[q0];
        qfl[1] = *(const bf16x8*)&Ql[q0 + 32];
    }

    f32x4 accO[4] = {};
    float m_run[4] = {-1e30f, -1e30f, -1e30f, -1e30f};
    float l_run[4] = {0.f, 0.f, 0.f, 0.f};

    const int sj = tid >> 3;
    const int sc = ((tid & 7) ^ (sj & 7)) * 8;   // inverse-swizzled src column
    const size_t kb = (size_t)bh * 32768;

    const char* sKhB = (const char*)sKh;
    const char* sKlB = (const char*)sKl;
    const char* sVtB = (const char*)sVt;
    char* sPB = (char*)sP;
    const int wpb = w * 2048;

    for (int t = 0; t < 8; ++t) {
        const int j0 = t * 64;
        __syncthreads();   // (A) done reading prev K/V
        stage16(&Kh[kb + (size_t)(j0 + sj) * 64 + sc], &sKh[tid * 8]);
        stage16(&Kh[kb + (size_t)(j0 + sj + 32) * 64 + sc], &sKh[(tid + 256) * 8]);
        stage16(&Kl[kb + (size_t)(j0 + sj) * 64 + sc], &sKl[tid * 8]);
        stage16(&Kl[kb + (size_t)(j0 + sj + 32) * 64 + sc], &sKl[(tid + 256) * 8]);
        stage16(&Vtb[kb + (size_t)sj * 512 + j0 + sc], &sVt[tid * 8]);
        stage16(&Vtb[kb + (size_t)(sj + 32) * 512 + j0 + sc], &sVt[(tid + 256) * 8]);
        __syncthreads();   // (B) staged visible (vmcnt drained)

        // prefetch hop/edge indices for this tile
        int hv[16], ev[16];
        {
            const size_t rb = ((size_t)b * 512 + i0 + w * 16 + lhi * 4) * 512 + j0 + l15;
            const int* hp = hop + rb;
            const int* ep = edge + rb;
#pragma unroll
            for (int r = 0; r < 4; ++r)
#pragma unroll
                for (int cf = 0; cf < 4; ++cf) {
                    hv[cf * 4 + r] = hp[r * 512 + cf * 16];
                    ev[cf * 4 + r] = ep[r * 512 + cf * 16];
                }
        }

        // ---- QK^T (split-bf16: hh + hl + lh) ----
        f32x4 S[4] = {};
#pragma unroll
        for (int ks = 0; ks < 2; ++ks) {
            const int rb2 = (ks * 64 + lhi * 16) ^ xorv;
#pragma unroll
            for (int cf = 0; cf < 4; ++cf) {
                const int jrow = (cf * 16 + l15) * 128;
                bf16x8 kh_ = *(const bf16x8*)(sKhB + jrow + rb2);
                bf16x8 kl_ = *(const bf16x8*)(sKlB + jrow + rb2);
                S[cf] = __builtin_amdgcn_mfma_f32_16x16x32_bf16(qfh[ks], kh_, S[cf], 0, 0, 0);
                S[cf] = __builtin_amdgcn_mfma_f32_16x16x32_bf16(qfh[ks], kl_, S[cf], 0, 0, 0);
                S[cf] = __builtin_amdgcn_mfma_f32_16x16x32_bf16(qfl[ks], kh_, S[cf], 0, 0, 0);
            }
        }

        // ---- softmax (rows lhi*4+r within wave strip; 16-lane groups) ----
        float val[16];
#pragma unroll
        for (int cf = 0; cf < 4; ++cf)
#pragma unroll
            for (int r = 0; r < 4; ++r) {
                const int rg = w * 16 + lhi * 4 + r;
                val[cf * 4 + r] = (S[cf][r] + bf2f(sShop[rg * 32 + hv[cf * 4 + r]])
                                   + bf2f(sSedge[rg * 64 + ev[cf * 4 + r]])) * SCALE;
            }
        float tmax[4];
#pragma unroll
        for (int r = 0; r < 4; ++r) {
            float tm = fmaxf(fmaxf(val[r], val[4 + r]), fmaxf(val[8 + r], val[12 + r]));
            tm = fmaxf(tm, __shfl_xor(tm, 1));
            tm = fmaxf(tm, __shfl_xor(tm, 2));
            tm = fmaxf(tm, __shfl_xor(tm, 4));
            tm = fmaxf(tm, __shfl_xor(tm, 8));
            tmax[r] = tm;
        }
        const bool need = (tmax[0] > m_run[0] + 10.f) || (tmax[1] > m_run[1] + 10.f) ||
                          (tmax[2] > m_run[2] + 10.f) || (tmax[3] > m_run[3] + 10.f);
        if (__any(need)) {   // rare after tile 0 (defer-max)
#pragma unroll
            for (int r = 0; r < 4; ++r) {
                const float mn = fmaxf(m_run[r], tmax[r]);
                const float al = __expf(m_run[r] - mn);
                m_run[r] = mn;
                l_run[r] *= al;
                accO[0][r] *= al; accO[1][r] *= al;
                accO[2][r] *= al; accO[3][r] *= al;
                const int rg = w * 16 + lhi * 4 + r;
                vha[rg * 33 + l15] *= al;
                vha[rg * 33 + 16 + l15] *= al;
                vea[rg * 65 + l15] *= al;
                vea[rg * 65 + 16 + l15] *= al;
                vea[rg * 65 + 32 + l15] *= al;
                vea[rg * 65 + 48 + l15] *= al;
            }
            asm volatile("" ::: "memory");
        }
        float p[16];
        float ps[4] = {0.f, 0.f, 0.f, 0.f};
#pragma unroll
        for (int cf = 0; cf < 4; ++cf)
#pragma unroll
            for (int r = 0; r < 4; ++r) {
                const float pe = __expf(val[cf * 4 + r] - m_run[r]);
                p[cf * 4 + r] = pe;
                ps[r] += pe;
            }
#pragma unroll
        for (int r = 0; r < 4; ++r) {
            float s_ = ps[r];
            s_ += __shfl_xor(s_, 1);
            s_ += __shfl_xor(s_, 2);
            s_ += __shfl_xor(s_, 4);
            s_ += __shfl_xor(s_, 8);
            l_run[r] += s_;
        }
        // bins (wave-private rows) + P -> LDS (bf16, swizzled)
#pragma unroll
        for (int cf = 0; cf < 4; ++cf)
#pragma unroll
            for (int r = 0; r < 4; ++r) {
                const int rg = w * 16 + lhi * 4 + r;
                atomicAdd(&vha[rg * 33 + hv[cf * 4 + r]], p[cf * 4 + r]);
                atomicAdd(&vea[rg * 65 + ev[cf * 4 + r]], p[cf * 4 + r]);
                const int rl = lhi * 4 + r;
                *(ushort*)(sPB + wpb + rl * 128 +
                           ((cf * 32 + l15 * 2) ^ ((rl & 7) << 4))) = f2bf(p[cf * 4 + r]);
            }
        asm volatile("" ::: "memory");   // wave-internal P visibility

        // ---- PV (single bf16) ----
#pragma unroll
        for (int ks = 0; ks < 2; ++ks) {
            const int rb2 = (ks * 64 + lhi * 16) ^ xorv;
            bf16x8 pa = *(const bf16x8*)(sPB + wpb + l15 * 128 + rb2);
#pragma unroll
            for (int cf = 0; cf < 4; ++cf) {
                bf16x8 vb = *(const bf16x8*)(sVtB + (cf * 16 + l15) * 128 + rb2);
                accO[cf] = __builtin_amdgcn_mfma_f32_16x16x32_bf16(pa, vb, accO[cf], 0, 0, 0);
            }
        }
    }
    asm volatile("" ::: "memory");

    // ---- epilogue: normalize, + vha@vhe + vea@vee, store ----
    float inv[4];
#pragma unroll
    for (int r = 0; r < 4; ++r) inv[r] = 1.0f / l_run[r];
    float o[16];
#pragma unroll
    for (int cf = 0; cf < 4; ++cf)
#pragma unroll
        for (int r = 0; r < 4; ++r) o[cf * 4 + r] = accO[cf][r] * inv[r];

    const int rgb = w * 16 + lhi * 4;
    for (int tt = 0; tt < 32; ++tt) {
        float wn[4];
#pragma unroll
        for (int r = 0; r < 4; ++r) wn[r] = vha[(rgb + r) * 33 + tt] * inv[r];
        const float* g = vhe + (size_t)tt * 1024 + h * 64 + l15;
#pragma unroll
        for (int cf = 0; cf < 4; ++cf) {
            const float gv = g[cf * 16];
#pragma unroll
            for (int r = 0; r < 4; ++r) o[cf * 4 + r] += wn[r] * gv;
        }
    }
    for (int tt = 0; tt < 64; ++tt) {
        float wn[4];
#pragma unroll
        for (int r = 0; r < 4; ++r) wn[r] = vea[(rgb + r) * 65 + tt] * inv[r];
        const float* g = vee + (size_t)tt * 1024 + h * 64 + l15;
#pragma unroll
        for (int cf = 0; cf < 4; ++cf) {
            const float gv = g[cf * 16];
#pragma unroll
            for (int r = 0; r < 4; ++r) o[cf * 4 + r] += wn[r] * gv;
        }
    }
#pragma unroll
    for (int r = 0; r < 4; ++r) {
        float* yp = Y + ((size_t)b * 512 + i0 + rgb + r) * 1024 + h * 64 + l15;
#pragma unroll
        for (int cf = 0; cf < 4; ++cf) yp[cf * 16] = o[cf * 4 + r];
    }
}

// ---------------------------------------------------------------------------
extern "C" void kernel_launch(void* const* d_in, const int* in_sizes, int n_in,
                              void* d_out, int out_size, void* d_ws, size_t ws_size,
                              hipStream_t stream)
{
    (void)in_sizes; (void)n_in; (void)out_size; (void)ws_size;
    const float* x   = (const float*)d_in[0];
    const float* qhe = (const float*)d_in[1];
    const float* qee = (const float*)d_in[2];
    const float* khe = (const float*)d_in[3];
    const float* kee = (const float*)d_in[4];
    const float* vhe = (const float*)d_in[5];
    const float* vee = (const float*)d_in[6];
    const int*   hop = (const int*)d_in[7];
    const int*   edg = (const int*)d_in[8];
    const float* Wq = (const float*)d_in[9];  const float* bq = (const float*)d_in[10];
    const float* Wk = (const float*)d_in[11]; const float* bk = (const float*)d_in[12];
    const float* Wv = (const float*)d_in[13]; const float* bv = (const float*)d_in[14];
    const float* Wo = (const float*)d_in[15]; const float* bo = (const float*)d_in[16];

    ushort* Qh    = (ushort*)d_ws;
    ushort* Ql    = Qh + 8388608;
    ushort* Kh    = Ql + 8388608;
    ushort* Kl    = Kh + 8388608;
    ushort* VtB   = Kl + 8388608;
    ushort* ShopB = VtB + 8388608;
    ushort* SedgeB= ShopB + 4194304;
    float*  Yb    = (float*)(SedgeB + 8388608);
    ushort* xh    = (ushort*)(Yb + 8388608);
    ushort* xl    = xh + 8388608;
    ushort* wh    = xl + 8388608;
    ushort* wl    = wh + 1048576;

    const dim3 gG(64, 16);

    split_bf16<<<2048, 256, 0, stream>>>(x, xh, xl, 8388608);
    split_bf16<<<512, 256, 0, stream>>>(Wq, wh, wl, 1048576);
    gemm_mfma<<<gG, 256, 0, stream>>>(xh, xl, wh, wl, bq, nullptr, Qh, Ql, 1);
    split_bf16<<<512, 256, 0, stream>>>(Wk, wh, wl, 1048576);
    gemm_mfma<<<gG, 256, 0, stream>>>(xh, xl, wh, wl, bk, nullptr, Kh, Kl, 1);
    split_bf16<<<512, 256, 0, stream>>>(Wv, wh, wl, 1048576);
    gemm_mfma<<<gG, 256, 0, stream>>>(xh, xl, wh, wl, bv, nullptr, VtB, nullptr, 2);

    type_scores<<<2048, 256, 0, stream>>>(Qh, Ql, Kh, Kl, qhe, qee, khe, kee,
                                          ShopB, SedgeB);
    attn_mfma<<<2048, 256, 0, stream>>>(Qh, Ql, Kh, Kl, VtB, ShopB, SedgeB,
                                        hop, edg, vhe, vee, Yb);

    split_bf16<<<2048, 256, 0, stream>>>(Yb, xh, xl, 8388608);
    split_bf16<<<512, 256, 0, stream>>>(Wo, wh, wl, 1048576);
    gemm_mfma<<<gG, 256, 0, stream>>>(xh, xl, wh, wl, bo, (float*)d_out,
                                      nullptr, nullptr, 0);
}